// Round 11
// baseline (184.460 us; speedup 1.0000x reference)
//
#include <hip/hip_runtime.h>

#define BB   64
#define TT   200
#define NIN  128
#define NN   2048
#define NOUT 20

#define S    25     // speculation window (TT = 8 * 25)
#define NWIN 8
#define ACAP 64     // spec spike list capacity per step
#define BCAP 128    // replay spike list capacity

typedef __attribute__((ext_vector_type(8))) short short8;
typedef __attribute__((ext_vector_type(4))) float f32x4;
typedef __attribute__((ext_vector_type(4))) _Float16 h16x4;

// ---- bf16 split: x = hi + lo + eps, |eps| <= 2^-18 |x| ----------------------
__device__ __forceinline__ void bf16split(float x, ushort& h, ushort& l) {
    unsigned u = __float_as_uint(x);
    unsigned hb = (u + 0x7FFFu + ((u >> 16) & 1u)) >> 16;
    h = (ushort)hb;
    float xh = __uint_as_float(hb << 16);
    float xl = x - xh;                      // exact
    unsigned v = __float_as_uint(xl);
    l = (ushort)((v + 0x7FFFu + ((v >> 16) & 1u)) >> 16);
}

// ---- pre-kernel 1: split+repack A (inputs) into MFMA-fragment order --------
// Ap layout: [row_blk=800][kc=4][hl=2][lane=64][8] ushort
__global__ __launch_bounds__(256) void repack_a(
    const float* __restrict__ X, ushort* __restrict__ Ap)
{
    const int blk  = blockIdx.x;            // row_blk 0..799
    const int tid  = threadIdx.x;
    const int kc   = tid >> 6;
    const int lane = tid & 63;
    const int lr   = lane & 15, lg = lane >> 4;

    const float* src = X + (size_t)(blk * 16 + lr) * NIN + kc * 32 + lg * 8;
    float f[8];
    *(float4*)(f)     = *(const float4*)(src);
    *(float4*)(f + 4) = *(const float4*)(src + 4);

    short8 hv, lv;
    #pragma unroll
    for (int j = 0; j < 8; ++j) {
        ushort h, l;
        bf16split(f[j], h, l);
        hv[j] = (short)h; lv[j] = (short)l;
    }
    ushort* dst = Ap + (size_t)(blk * 4 + kc) * 1024 + lane * 8;
    *(short8*)(dst)       = hv;
    *(short8*)(dst + 512) = lv;
}

// ---- pre-kernel 2: split + transpose + repack w_in [128][2048] -------------
// Bp layout: [n_blk=128][kc=4][hl=2][lane=64][8] ushort
__global__ __launch_bounds__(256) void repack_b(
    const float* __restrict__ W, ushort* __restrict__ Bp)
{
    const int blk  = blockIdx.x;            // n_blk 0..127
    const int tid  = threadIdx.x;
    const int kc   = tid >> 6;
    const int lane = tid & 63;
    const int lr   = lane & 15, lg = lane >> 4;

    const float* src = W + (size_t)(kc * 32 + lg * 8) * NN + blk * 16 + lr;
    float f[8];
    #pragma unroll
    for (int j = 0; j < 8; ++j) f[j] = src[(size_t)j * NN];

    short8 hv, lv;
    #pragma unroll
    for (int j = 0; j < 8; ++j) {
        ushort h, l;
        bf16split(f[j], h, l);
        hv[j] = (short)h; lv[j] = (short)l;
    }
    ushort* dst = Bp + (size_t)(blk * 4 + kc) * 1024 + lane * 8;
    *(short8*)(dst)       = hv;
    *(short8*)(dst + 512) = lv;
}

// ---- MFMA GEMM with per-kc LDS staging + fp16 epilogue (R9/R10, verified) ---
// h1 = Ah*Bh + Ah*Bl + Al*Bh  (verified product set / chain order)
__global__ __launch_bounds__(256, 2) void h1_mfma(
    const ushort* __restrict__ Ap, const ushort* __restrict__ Bp,
    _Float16* __restrict__ C)
{
    __shared__ ushort sbuf[2][16][1024];   // [dbuf][side*8+chunk][hl*512+lane*8]

    const int l   = blockIdx.y * gridDim.x + blockIdx.x;  // 0..1599
    const int nl  = (l & 7) * 200 + (l >> 3);             // bijective XCD chunk
    const int bx  = nl & 15, by = nl >> 4;

    const int tid  = threadIdx.x;
    const int w_   = tid >> 6, lane = tid & 63;
    const int lr   = lane & 15, lg = lane >> 4;
    const int m0   = by * 128, n0 = bx * 128;
    const int wr   = (w_ >> 1) * 64, wc = (w_ & 1) * 64;

    const ushort* pAs = Ap + (size_t)(m0 >> 4) * 4096;    // row_blk stride 4096
    const ushort* pBs = Bp + (size_t)(n0 >> 4) * 4096;

    // wave w_ stages (chunk,hl) pairs idx = w_*8 .. w_*8+7 of 32 total
#define STAGE(kc, nb)                                                        \
    do {                                                                     \
        _Pragma("unroll")                                                    \
        for (int i_ = 0; i_ < 8; ++i_) {                                     \
            const int idx_   = w_ * 8 + i_;                                  \
            const int side_  = idx_ >> 4;                                    \
            const int chunk_ = (idx_ >> 1) & 7;                              \
            const int hl_    = idx_ & 1;                                     \
            const ushort* g_ = (side_ ? pBs : pAs) + chunk_ * 4096           \
                               + (kc) * 1024 + hl_ * 512 + lane * 8;         \
            ushort* d_ = &sbuf[nb][idx_ >> 1][hl_ * 512];                    \
            __builtin_amdgcn_global_load_lds(                                \
                (const __attribute__((address_space(1))) void*)g_,           \
                (__attribute__((address_space(3))) void*)d_, 16, 0, 0);      \
        }                                                                    \
    } while (0)

    f32x4 acc[4][4];
    const f32x4 z = {0.f, 0.f, 0.f, 0.f};
    #pragma unroll
    for (int rb = 0; rb < 4; ++rb)
        #pragma unroll
        for (int cb = 0; cb < 4; ++cb) acc[rb][cb] = z;

    STAGE(0, 0);
    __syncthreads();    // drains vmcnt: stage(0) complete

    const int ar = wr >> 4;        // A chunk base (0 or 4)
    const int br = 8 + (wc >> 4);  // B chunk base (8 or 12)

    #pragma unroll
    for (int kc = 0; kc < 4; ++kc) {
        const int cb_ = kc & 1;
        if (kc < 3) STAGE(kc + 1, cb_ ^ 1);     // prefetch under compute

        short8 fah[4], fal[4], fbh[4], fbl[4];
        #pragma unroll
        for (int rb = 0; rb < 4; ++rb) {
            fah[rb] = *(const short8*)(&sbuf[cb_][ar + rb][lane * 8]);
            fal[rb] = *(const short8*)(&sbuf[cb_][ar + rb][512 + lane * 8]);
        }
        #pragma unroll
        for (int cb = 0; cb < 4; ++cb) {
            fbh[cb] = *(const short8*)(&sbuf[cb_][br + cb][lane * 8]);
            fbl[cb] = *(const short8*)(&sbuf[cb_][br + cb][512 + lane * 8]);
        }
        #pragma unroll
        for (int rb = 0; rb < 4; ++rb)
            #pragma unroll
            for (int cb = 0; cb < 4; ++cb) {
                acc[rb][cb] = __builtin_amdgcn_mfma_f32_16x16x32_bf16(
                    fbh[cb], fah[rb], acc[rb][cb], 0, 0, 0);
                acc[rb][cb] = __builtin_amdgcn_mfma_f32_16x16x32_bf16(
                    fbl[cb], fah[rb], acc[rb][cb], 0, 0, 0);
                acc[rb][cb] = __builtin_amdgcn_mfma_f32_16x16x32_bf16(
                    fbh[cb], fal[rb], acc[rb][cb], 0, 0, 0);
            }
        if (kc < 3) __syncthreads();   // stage(kc+1) done; buf[cb_] reads done
    }
#undef STAGE

    #pragma unroll
    for (int rb = 0; rb < 4; ++rb) {
        _Float16* Crow = C + (size_t)(m0 + wr + rb * 16 + lr) * NN
                           + n0 + wc + lg * 4;
        #pragma unroll
        for (int cb = 0; cb < 4; ++cb) {
            h16x4 hv;
            hv[0] = (_Float16)acc[rb][cb][0];
            hv[1] = (_Float16)acc[rb][cb][1];
            hv[2] = (_Float16)acc[rb][cb][2];
            hv[3] = (_Float16)acc[rb][cb][3];
            *(h16x4*)(Crow + cb * 16) = hv;
        }
    }
}

// ---------------- Phase 2+3: speculative windowed scan -----------------------
// NEW (this round): S=25, NWIN=8 — amortize the fixed per-window overhead
// (barrier + latency tail + epilogue, the measured ~4000cy that data-volume
// and sync levers never touched) over 3x more steps. Spec-pass push values
// now use a sequentially-decayed register copy wpd (bit-exact vs reference's
// per-step wp *= 0.99, replacing the 0.99^j constant table).
__global__ __launch_bounds__(512) void snn_scan(
    const _Float16* __restrict__ h1, const float* __restrict__ w,
    const float* __restrict__ w_signs, const float* __restrict__ pvec,
    const float* __restrict__ w_out, float* __restrict__ out)
{
    const int b   = blockIdx.x;
    const int tid = threadIdx.x;
    const int n0  = tid << 2;

    __shared__ int   s_amask[2];
    __shared__ int   s_acnt[2][S];
    __shared__ int   s_aidx[2][S][ACAP];
    __shared__ float s_aval[2][S][ACAP];
    __shared__ int   s_bcnt[2];
    __shared__ int   s_bidx[2][BCAP];
    __shared__ float s_bval[2][BCAP];

    if (tid < 2) { s_amask[tid] = 0; s_bcnt[tid] = 0; }
    if (tid < 2 * S) ((int*)s_acnt)[tid] = 0;

    float4 mem = {0.f,0.f,0.f,0.f}, wp = {0.f,0.f,0.f,0.f};
    const float4 p4 = *(const float4*)(pvec + n0);
    const float4 sg = *(const float4*)(w_signs + n0);
    float4 depr;
    depr.x = (p4.x < 0.f) ? 1.f : 0.f;  depr.y = (p4.y < 0.f) ? 1.f : 0.f;
    depr.z = (p4.z < 0.f) ? 1.f : 0.f;  depr.w = (p4.w < 0.f) ? 1.f : 0.f;

    const _Float16* hb = h1 + (size_t)b * TT * NN + n0;
    float* outb = out + (size_t)b * TT * NOUT + tid;   // used only if tid<20
    float o2 = 0.f;

    h16x4 PA[S], PB[S];
    #pragma unroll
    for (int j = 0; j < S; ++j) PA[j] = *(const h16x4*)(hb + (size_t)j * NN);
    __syncthreads();   // LDS init visible

#define RAWBAR()                                              \
    do { asm volatile("s_waitcnt lgkmcnt(0)" ::: "memory");   \
         __builtin_amdgcn_s_barrier();                        \
         asm volatile("" ::: "memory"); } while (0)

#define CVT4(v) { (float)(v)[0], (float)(v)[1], (float)(v)[2], (float)(v)[3] }

    auto window = [&](h16x4 (&Pc)[S], h16x4 (&Pf)[S], int wnd) {
        const int p  = wnd & 1;
        const int t0 = wnd * S;
        const float4 memB = mem, wpB = wp;

        // wpd: sequentially decayed copy of wp (bit-exact push values).
        float4 wpd = wp;

        // ---- slim speculative pass: syn = 0, wp frozen (wpd tracks decay) --
        #pragma unroll
        for (int j = 0; j < S; ++j) {
            const float4 a = CVT4(Pc[j]);
            int tp = t0 + j + S; if (tp > TT - 1) tp = TT - 1;
            Pf[j] = *(const h16x4*)(hb + (size_t)tp * NN);   // depth-1 fetch

            // spike test on PRE-update mem (reference semantics)
            const float mx = fmaxf(fmaxf(mem.x, mem.y), fmaxf(mem.z, mem.w));
            if (__builtin_expect(mx > 1.f, 0)) {
                const bool f0 = mem.x > 1.f, f1 = mem.y > 1.f,
                           f2 = mem.z > 1.f, f3 = mem.w > 1.f;
                atomicOr(&s_amask[p], 1 << j);
                if (f0) { int k = atomicAdd(&s_acnt[p][j], 1);
                          if (k < ACAP) { s_aidx[p][j][k] = n0;
                                          s_aval[p][j][k] = (1.f + wpd.x) * sg.x; } }
                if (f1) { int k = atomicAdd(&s_acnt[p][j], 1);
                          if (k < ACAP) { s_aidx[p][j][k] = n0 + 1;
                                          s_aval[p][j][k] = (1.f + wpd.y) * sg.y; } }
                if (f2) { int k = atomicAdd(&s_acnt[p][j], 1);
                          if (k < ACAP) { s_aidx[p][j][k] = n0 + 2;
                                          s_aval[p][j][k] = (1.f + wpd.z) * sg.z; } }
                if (f3) { int k = atomicAdd(&s_acnt[p][j], 1);
                          if (k < ACAP) { s_aidx[p][j][k] = n0 + 3;
                                          s_aval[p][j][k] = (1.f + wpd.w) * sg.w; } }
                mem.x = fmaf(0.9f, mem.x, a.x) - (f0 ? 1.f : 0.f);
                mem.y = fmaf(0.9f, mem.y, a.y) - (f1 ? 1.f : 0.f);
                mem.z = fmaf(0.9f, mem.z, a.z) - (f2 ? 1.f : 0.f);
                mem.w = fmaf(0.9f, mem.w, a.w) - (f3 ? 1.f : 0.f);
            } else {
                mem.x = fmaf(0.9f, mem.x, a.x);
                mem.y = fmaf(0.9f, mem.y, a.y);
                mem.z = fmaf(0.9f, mem.z, a.z);
                mem.w = fmaf(0.9f, mem.w, a.w);
            }
            wpd.x *= 0.99f; wpd.y *= 0.99f; wpd.z *= 0.99f; wpd.w *= 0.99f;
        }

        RAWBAR();                    // no vmcnt drain: prefetch stays in flight
        const int mask = s_amask[p];

        if (__builtin_expect(mask == 0, 1)) {   // ---- clean window ----
            wp = wpd;                // sequential decay, bit-exact
            if (tid < NOUT) {
                #pragma unroll
                for (int j = 0; j < S; ++j) {
                    o2 = 0.9f * o2;
                    outb[(size_t)(t0 + j) * NOUT] = o2;
                }
            }
            return;
        }

        // ---- dirty window: rollback + exact replay (slim sync) ----
        const int tstar = __ffs(mask) - 1;

        // prefetch t* w-rows early: list is exact & complete; hide gather
        // latency under the j<t* register replay. (cnt is block-uniform.)
        int cntS = s_acnt[p][tstar]; if (cntS > ACAP) cntS = ACAP;
        int   pidx[4];
        float pval[4];
        float4 wpre[4];
        #pragma unroll
        for (int m_ = 0; m_ < 4; ++m_) {
            if (m_ < cntS) {
                pidx[m_] = s_aidx[p][tstar][m_];
                pval[m_] = s_aval[p][tstar][m_];
                wpre[m_] = *(const float4*)(w + (size_t)pidx[m_] * NN + n0);
            }
        }

        mem = memB; wp = wpB;
        #pragma unroll
        for (int j = 0; j < S; ++j) {
            const float4 a = CVT4(Pc[j]);
            if (j < tstar) {          // certified spike-free
                mem.x = fmaf(0.9f, mem.x, a.x);
                mem.y = fmaf(0.9f, mem.y, a.y);
                mem.z = fmaf(0.9f, mem.z, a.z);
                mem.w = fmaf(0.9f, mem.w, a.w);
                wp.x *= 0.99f; wp.y *= 0.99f; wp.z *= 0.99f; wp.w *= 0.99f;
                if (tid < NOUT) { o2 = 0.9f * o2;
                                  outb[(size_t)(t0 + j) * NOUT] = o2; }
            } else if (j == tstar) {  // spec list at t* is exact & complete
                const bool f0 = mem.x > 1.f, f1 = mem.y > 1.f,   // pre-update
                           f2 = mem.z > 1.f, f3 = mem.w > 1.f;
                float4 syn = {0.f,0.f,0.f,0.f};
                #pragma unroll
                for (int m_ = 0; m_ < 4; ++m_) {
                    if (m_ < cntS) {
                        syn.x = fmaf(pval[m_], fabsf(wpre[m_].x), syn.x);
                        syn.y = fmaf(pval[m_], fabsf(wpre[m_].y), syn.y);
                        syn.z = fmaf(pval[m_], fabsf(wpre[m_].z), syn.z);
                        syn.w = fmaf(pval[m_], fabsf(wpre[m_].w), syn.w);
                    }
                }
                for (int m = 4; m < cntS; ++m) {
                    const int nm = s_aidx[p][tstar][m];
                    const float vm = s_aval[p][tstar][m];
                    const float4 wr = *(const float4*)(w + (size_t)nm * NN + n0);
                    syn.x = fmaf(vm, fabsf(wr.x), syn.x);
                    syn.y = fmaf(vm, fabsf(wr.y), syn.y);
                    syn.z = fmaf(vm, fabsf(wr.z), syn.z);
                    syn.w = fmaf(vm, fabsf(wr.w), syn.w);
                }
                if (tid < NOUT) {
                    float c = 0.f;
                    for (int m = 0; m < cntS; ++m)
                        c += w_out[(size_t)s_aidx[p][tstar][m] * NOUT + tid];
                    o2 = 0.9f * o2 + c;
                    outb[(size_t)(t0 + j) * NOUT] = o2;
                }
                mem.x = fmaf(0.9f, mem.x, a.x) + syn.x - (f0 ? 1.f : 0.f);
                mem.y = fmaf(0.9f, mem.y, a.y) + syn.y - (f1 ? 1.f : 0.f);
                mem.z = fmaf(0.9f, mem.z, a.z) + syn.z - (f2 ? 1.f : 0.f);
                mem.w = fmaf(0.9f, mem.w, a.w) + syn.w - (f3 ? 1.f : 0.f);
                wp.x = f0 ? 0.99f*wp.x + p4.x*(1.f + depr.x*wp.x) : 0.99f*wp.x;
                wp.y = f1 ? 0.99f*wp.y + p4.y*(1.f + depr.y*wp.y) : 0.99f*wp.y;
                wp.z = f2 ? 0.99f*wp.z + p4.z*(1.f + depr.z*wp.z) : 0.99f*wp.z;
                wp.w = f3 ? 0.99f*wp.w + p4.w*(1.f + depr.w*wp.w) : 0.99f*wp.w;
            } else {                  // slow step: 1 barrier; exchange only if
                                      // spikes actually landed this step
                const int par = j & 1;
                const bool f0 = mem.x > 1.f, f1 = mem.y > 1.f,   // pre-update
                           f2 = mem.z > 1.f, f3 = mem.w > 1.f;
                if (f0 | f1 | f2 | f3) {
                    if (f0) { int k = atomicAdd(&s_bcnt[par], 1); if (k < BCAP) {
                              s_bidx[par][k] = n0;     s_bval[par][k] = (1.f + wp.x) * sg.x; } }
                    if (f1) { int k = atomicAdd(&s_bcnt[par], 1); if (k < BCAP) {
                              s_bidx[par][k] = n0 + 1; s_bval[par][k] = (1.f + wp.y) * sg.y; } }
                    if (f2) { int k = atomicAdd(&s_bcnt[par], 1); if (k < BCAP) {
                              s_bidx[par][k] = n0 + 2; s_bval[par][k] = (1.f + wp.z) * sg.z; } }
                    if (f3) { int k = atomicAdd(&s_bcnt[par], 1); if (k < BCAP) {
                              s_bidx[par][k] = n0 + 3; s_bval[par][k] = (1.f + wp.w) * sg.w; } }
                }
                RAWBAR();             // pushes + cnt visible
                int cnt = s_bcnt[par]; if (cnt > BCAP) cnt = BCAP;
                float4 syn = {0.f,0.f,0.f,0.f};
                if (__builtin_expect(cnt != 0, 0)) {   // rare secondary spikes
                    for (int m = 0; m < cnt; ++m) {
                        const int nm = s_bidx[par][m];
                        const float vm = s_bval[par][m];
                        const float4 wr = *(const float4*)(w + (size_t)nm * NN + n0);
                        syn.x = fmaf(vm, fabsf(wr.x), syn.x);
                        syn.y = fmaf(vm, fabsf(wr.y), syn.y);
                        syn.z = fmaf(vm, fabsf(wr.z), syn.z);
                        syn.w = fmaf(vm, fabsf(wr.w), syn.w);
                    }
                }
                if (tid < NOUT) {
                    float c = 0.f;
                    for (int m = 0; m < cnt; ++m)
                        c += w_out[(size_t)s_bidx[par][m] * NOUT + tid];
                    o2 = 0.9f * o2 + c;
                    outb[(size_t)(t0 + j) * NOUT] = o2;
                }
                mem.x = fmaf(0.9f, mem.x, a.x) + syn.x - (f0 ? 1.f : 0.f);
                mem.y = fmaf(0.9f, mem.y, a.y) + syn.y - (f1 ? 1.f : 0.f);
                mem.z = fmaf(0.9f, mem.z, a.z) + syn.z - (f2 ? 1.f : 0.f);
                mem.w = fmaf(0.9f, mem.w, a.w) + syn.w - (f3 ? 1.f : 0.f);
                wp.x = f0 ? 0.99f*wp.x + p4.x*(1.f + depr.x*wp.x) : 0.99f*wp.x;
                wp.y = f1 ? 0.99f*wp.y + p4.y*(1.f + depr.y*wp.y) : 0.99f*wp.y;
                wp.z = f2 ? 0.99f*wp.z + p4.z*(1.f + depr.z*wp.z) : 0.99f*wp.z;
                wp.w = f3 ? 0.99f*wp.w + p4.w*(1.f + depr.w*wp.w) : 0.99f*wp.w;
                if (__builtin_expect(cnt != 0, 0)) {
                    RAWBAR();         // all reads of B-list done
                    if (tid == 0) s_bcnt[par] = 0;
                }
                // cnt==0: nothing written, buffer already 0 -> no 2nd barrier
            }
        }
        RAWBAR();                     // all A-list reads done before reset
        if (tid < S) s_acnt[p][tid] = 0;
        else if (tid == S) s_amask[p] = 0;
    };

    // NWIN = 8 (even): exact pairs, no tail window.
    for (int wnd = 0; wnd < NWIN; wnd += 2) {
        window(PA, PB, wnd);
        window(PB, PA, wnd + 1);
    }
#undef CVT4
#undef RAWBAR
}

// ---------------- launch ----------------------------------------------------
extern "C" void kernel_launch(void* const* d_in, const int* in_sizes, int n_in,
                              void* d_out, int out_size, void* d_ws, size_t ws_size,
                              hipStream_t stream) {
    (void)in_sizes; (void)n_in; (void)out_size; (void)ws_size;
    const float* inputs  = (const float*)d_in[0];
    const float* w       = (const float*)d_in[1];
    const float* w_in    = (const float*)d_in[2];
    const float* w_out   = (const float*)d_in[3];
    const float* w_signs = (const float*)d_in[4];
    const float* p       = (const float*)d_in[5];
    float* out = (float*)d_out;

    const size_t H1B = (size_t)BB * TT * NN * 2;      // 52,428,800 (h1 fp16)
    const size_t APB = (size_t)800 * 4096 * 2;        //  6,553,600 (A packed)

    _Float16* h1 = (_Float16*)d_ws;
    ushort*   Ap = (ushort*)((char*)d_ws + H1B);
    ushort*   Bp = (ushort*)((char*)d_ws + H1B + APB);

    repack_a<<<800, 256, 0, stream>>>(inputs, Ap);
    repack_b<<<128, 256, 0, stream>>>(w_in, Bp);

    dim3 gg(NN / 128, (BB * TT) / 128);               // (16, 100)
    h1_mfma<<<gg, 256, 0, stream>>>(Ap, Bp, h1);

    snn_scan<<<BB, 512, 0, stream>>>(h1, w, w_signs, p, w_out, out);
}

// Round 12
// 94.398 us; speedup vs baseline: 1.9541x; 1.9541x over previous
//
#include <hip/hip_runtime.h>

#define BB   64
#define TT   200
#define NIN  128
#define NN   2048
#define NOUT 20

#define S    8      // speculation window (TT = 25 * S)
#define NWIN 25
#define ACAP 64     // spec spike list capacity per step
#define BCAP 128    // replay spike list capacity

typedef __attribute__((ext_vector_type(8))) short short8;
typedef __attribute__((ext_vector_type(4))) float f32x4;
typedef __attribute__((ext_vector_type(4))) _Float16 h16x4;
typedef __attribute__((ext_vector_type(8))) _Float16 h16x8;

// ---- bf16 split: x = hi + lo + eps, |eps| <= 2^-18 |x| ----------------------
__device__ __forceinline__ void bf16split(float x, ushort& h, ushort& l) {
    unsigned u = __float_as_uint(x);
    unsigned hb = (u + 0x7FFFu + ((u >> 16) & 1u)) >> 16;
    h = (ushort)hb;
    float xh = __uint_as_float(hb << 16);
    float xl = x - xh;                      // exact
    unsigned v = __float_as_uint(xl);
    l = (ushort)((v + 0x7FFFu + ((v >> 16) & 1u)) >> 16);
}

// ---- pre-kernel 1: split+repack A (inputs) into MFMA-fragment order --------
// Ap layout: [row_blk=800][kc=4][hl=2][lane=64][8] ushort
__global__ __launch_bounds__(256) void repack_a(
    const float* __restrict__ X, ushort* __restrict__ Ap)
{
    const int blk  = blockIdx.x;            // row_blk 0..799
    const int tid  = threadIdx.x;
    const int kc   = tid >> 6;
    const int lane = tid & 63;
    const int lr   = lane & 15, lg = lane >> 4;

    const float* src = X + (size_t)(blk * 16 + lr) * NIN + kc * 32 + lg * 8;
    float f[8];
    *(float4*)(f)     = *(const float4*)(src);
    *(float4*)(f + 4) = *(const float4*)(src + 4);

    short8 hv, lv;
    #pragma unroll
    for (int j = 0; j < 8; ++j) {
        ushort h, l;
        bf16split(f[j], h, l);
        hv[j] = (short)h; lv[j] = (short)l;
    }
    ushort* dst = Ap + (size_t)(blk * 4 + kc) * 1024 + lane * 8;
    *(short8*)(dst)       = hv;
    *(short8*)(dst + 512) = lv;
}

// ---- pre-kernel 2: split + transpose + repack w_in [128][2048] -------------
// Bp layout: [n_blk=128][kc=4][hl=2][lane=64][8] ushort
__global__ __launch_bounds__(256) void repack_b(
    const float* __restrict__ W, ushort* __restrict__ Bp)
{
    const int blk  = blockIdx.x;            // n_blk 0..127
    const int tid  = threadIdx.x;
    const int kc   = tid >> 6;
    const int lane = tid & 63;
    const int lr   = lane & 15, lg = lane >> 4;

    const float* src = W + (size_t)(kc * 32 + lg * 8) * NN + blk * 16 + lr;
    float f[8];
    #pragma unroll
    for (int j = 0; j < 8; ++j) f[j] = src[(size_t)j * NN];

    short8 hv, lv;
    #pragma unroll
    for (int j = 0; j < 8; ++j) {
        ushort h, l;
        bf16split(f[j], h, l);
        hv[j] = (short)h; lv[j] = (short)l;
    }
    ushort* dst = Bp + (size_t)(blk * 4 + kc) * 1024 + lane * 8;
    *(short8*)(dst)       = hv;
    *(short8*)(dst + 512) = lv;
}

// ---- MFMA GEMM with per-kc LDS staging + fp16 epilogue (R9/R10, verified) ---
// h1 = Ah*Bh + Ah*Bl + Al*Bh  (verified product set / chain order)
__global__ __launch_bounds__(256, 2) void h1_mfma(
    const ushort* __restrict__ Ap, const ushort* __restrict__ Bp,
    _Float16* __restrict__ C)
{
    __shared__ ushort sbuf[2][16][1024];   // [dbuf][side*8+chunk][hl*512+lane*8]

    const int l   = blockIdx.y * gridDim.x + blockIdx.x;  // 0..1599
    const int nl  = (l & 7) * 200 + (l >> 3);             // bijective XCD chunk
    const int bx  = nl & 15, by = nl >> 4;

    const int tid  = threadIdx.x;
    const int w_   = tid >> 6, lane = tid & 63;
    const int lr   = lane & 15, lg = lane >> 4;
    const int m0   = by * 128, n0 = bx * 128;
    const int wr   = (w_ >> 1) * 64, wc = (w_ & 1) * 64;

    const ushort* pAs = Ap + (size_t)(m0 >> 4) * 4096;    // row_blk stride 4096
    const ushort* pBs = Bp + (size_t)(n0 >> 4) * 4096;

    // wave w_ stages (chunk,hl) pairs idx = w_*8 .. w_*8+7 of 32 total
#define STAGE(kc, nb)                                                        \
    do {                                                                     \
        _Pragma("unroll")                                                    \
        for (int i_ = 0; i_ < 8; ++i_) {                                     \
            const int idx_   = w_ * 8 + i_;                                  \
            const int side_  = idx_ >> 4;                                    \
            const int chunk_ = (idx_ >> 1) & 7;                              \
            const int hl_    = idx_ & 1;                                     \
            const ushort* g_ = (side_ ? pBs : pAs) + chunk_ * 4096           \
                               + (kc) * 1024 + hl_ * 512 + lane * 8;         \
            ushort* d_ = &sbuf[nb][idx_ >> 1][hl_ * 512];                    \
            __builtin_amdgcn_global_load_lds(                                \
                (const __attribute__((address_space(1))) void*)g_,           \
                (__attribute__((address_space(3))) void*)d_, 16, 0, 0);      \
        }                                                                    \
    } while (0)

    f32x4 acc[4][4];
    const f32x4 z = {0.f, 0.f, 0.f, 0.f};
    #pragma unroll
    for (int rb = 0; rb < 4; ++rb)
        #pragma unroll
        for (int cb = 0; cb < 4; ++cb) acc[rb][cb] = z;

    STAGE(0, 0);
    __syncthreads();    // drains vmcnt: stage(0) complete

    const int ar = wr >> 4;        // A chunk base (0 or 4)
    const int br = 8 + (wc >> 4);  // B chunk base (8 or 12)

    #pragma unroll
    for (int kc = 0; kc < 4; ++kc) {
        const int cb_ = kc & 1;
        if (kc < 3) STAGE(kc + 1, cb_ ^ 1);     // prefetch under compute

        short8 fah[4], fal[4], fbh[4], fbl[4];
        #pragma unroll
        for (int rb = 0; rb < 4; ++rb) {
            fah[rb] = *(const short8*)(&sbuf[cb_][ar + rb][lane * 8]);
            fal[rb] = *(const short8*)(&sbuf[cb_][ar + rb][512 + lane * 8]);
        }
        #pragma unroll
        for (int cb = 0; cb < 4; ++cb) {
            fbh[cb] = *(const short8*)(&sbuf[cb_][br + cb][lane * 8]);
            fbl[cb] = *(const short8*)(&sbuf[cb_][br + cb][512 + lane * 8]);
        }
        #pragma unroll
        for (int rb = 0; rb < 4; ++rb)
            #pragma unroll
            for (int cb = 0; cb < 4; ++cb) {
                acc[rb][cb] = __builtin_amdgcn_mfma_f32_16x16x32_bf16(
                    fbh[cb], fah[rb], acc[rb][cb], 0, 0, 0);
                acc[rb][cb] = __builtin_amdgcn_mfma_f32_16x16x32_bf16(
                    fbl[cb], fah[rb], acc[rb][cb], 0, 0, 0);
                acc[rb][cb] = __builtin_amdgcn_mfma_f32_16x16x32_bf16(
                    fbh[cb], fal[rb], acc[rb][cb], 0, 0, 0);
            }
        if (kc < 3) __syncthreads();   // stage(kc+1) done; buf[cb_] reads done
    }
#undef STAGE

    #pragma unroll
    for (int rb = 0; rb < 4; ++rb) {
        _Float16* Crow = C + (size_t)(m0 + wr + rb * 16 + lr) * NN
                           + n0 + wc + lg * 4;
        #pragma unroll
        for (int cb = 0; cb < 4; ++cb) {
            h16x4 hv;
            hv[0] = (_Float16)acc[rb][cb][0];
            hv[1] = (_Float16)acc[rb][cb][1];
            hv[2] = (_Float16)acc[rb][cb][2];
            hv[3] = (_Float16)acc[rb][cb][3];
            *(h16x4*)(Crow + cb * 16) = hv;
        }
    }
}

// ---------------- Phase 2+3: speculative windowed scan (R10 logic, 256 thr) --
// NEW (this round): 256 threads x 8 neurons — restores the 16B/lane load
// shape (h16x8) that was empirically fastest pre-fp16; halves load
// instructions and barrier-participant waves. S=8, small unrolls (R11
// lesson). All formulas identical to R10 (bit-exact-verified).
__global__ __launch_bounds__(256) void snn_scan(
    const _Float16* __restrict__ h1, const float* __restrict__ w,
    const float* __restrict__ w_signs, const float* __restrict__ pvec,
    const float* __restrict__ w_out, float* __restrict__ out)
{
    const int b   = blockIdx.x;
    const int tid = threadIdx.x;
    const int n0  = tid << 3;              // 8 neurons per thread

    __shared__ int   s_amask[2];
    __shared__ int   s_acnt[2][S];
    __shared__ int   s_aidx[2][S][ACAP];
    __shared__ float s_aval[2][S][ACAP];
    __shared__ int   s_bcnt[2];
    __shared__ int   s_bidx[2][BCAP];
    __shared__ float s_bval[2][BCAP];

    if (tid < 2) { s_amask[tid] = 0; s_bcnt[tid] = 0; }
    if (tid < 2 * S) ((int*)s_acnt)[tid] = 0;

    float4 mem0 = {0.f,0.f,0.f,0.f}, mem1 = {0.f,0.f,0.f,0.f};
    float4 wp0  = {0.f,0.f,0.f,0.f}, wp1  = {0.f,0.f,0.f,0.f};
    const float4 p40 = *(const float4*)(pvec + n0);
    const float4 p41 = *(const float4*)(pvec + n0 + 4);
    const float4 sg0 = *(const float4*)(w_signs + n0);
    const float4 sg1 = *(const float4*)(w_signs + n0 + 4);
    float4 dp0, dp1;
    dp0.x = (p40.x < 0.f) ? 1.f : 0.f;  dp0.y = (p40.y < 0.f) ? 1.f : 0.f;
    dp0.z = (p40.z < 0.f) ? 1.f : 0.f;  dp0.w = (p40.w < 0.f) ? 1.f : 0.f;
    dp1.x = (p41.x < 0.f) ? 1.f : 0.f;  dp1.y = (p41.y < 0.f) ? 1.f : 0.f;
    dp1.z = (p41.z < 0.f) ? 1.f : 0.f;  dp1.w = (p41.w < 0.f) ? 1.f : 0.f;

    const float P99[S] = {1.0f, 0.99f, 0.9801f, 0.970299f, 0.96059601f,
                          0.9509900499f, 0.941480149401f, 0.93206534790699f};
    const float P99_8 = 0.9227446944279201f;

    const _Float16* hb = h1 + (size_t)b * TT * NN + n0;
    float* outb = out + (size_t)b * TT * NOUT + tid;   // used only if tid<20
    float o2 = 0.f;

    h16x8 PA[S], PB[S];
    #pragma unroll
    for (int j = 0; j < S; ++j) PA[j] = *(const h16x8*)(hb + (size_t)j * NN);
    __syncthreads();   // LDS init visible

#define RAWBAR()                                              \
    do { asm volatile("s_waitcnt lgkmcnt(0)" ::: "memory");   \
         __builtin_amdgcn_s_barrier();                        \
         asm volatile("" ::: "memory"); } while (0)

#define CVTLO(v) { (float)(v)[0], (float)(v)[1], (float)(v)[2], (float)(v)[3] }
#define CVTHI(v) { (float)(v)[4], (float)(v)[5], (float)(v)[6], (float)(v)[7] }

// push one spiked neuron into the spec A-list
#define APUSH(J, NIDX, WPV, SGV)                                            \
    do { int k_ = atomicAdd(&s_acnt[p][J], 1);                              \
         if (k_ < ACAP) { s_aidx[p][J][k_] = (NIDX);                        \
                          s_aval[p][J][k_] = (1.f + (WPV) * P99[J]) * (SGV); } } while (0)
// push into the slow-path B-list (sequential wp, exact)
#define BPUSH(PAR, NIDX, WPV, SGV)                                          \
    do { int k_ = atomicAdd(&s_bcnt[PAR], 1);                               \
         if (k_ < BCAP) { s_bidx[PAR][k_] = (NIDX);                         \
                          s_bval[PAR][k_] = (1.f + (WPV)) * (SGV); } } while (0)
// mem update for one float4 group: m = 0.9m + a - spike
#define MEMUP(M, A, F0, F1, F2, F3)                                         \
    do { (M).x = fmaf(0.9f, (M).x, (A).x) - ((F0) ? 1.f : 0.f);             \
         (M).y = fmaf(0.9f, (M).y, (A).y) - ((F1) ? 1.f : 0.f);             \
         (M).z = fmaf(0.9f, (M).z, (A).z) - ((F2) ? 1.f : 0.f);             \
         (M).w = fmaf(0.9f, (M).w, (A).w) - ((F3) ? 1.f : 0.f); } while (0)
// wp update for one float4 group (post-spike rule)
#define WPUP(W, P, D, F0, F1, F2, F3)                                       \
    do { (W).x = (F0) ? 0.99f*(W).x + (P).x*(1.f + (D).x*(W).x) : 0.99f*(W).x; \
         (W).y = (F1) ? 0.99f*(W).y + (P).y*(1.f + (D).y*(W).y) : 0.99f*(W).y; \
         (W).z = (F2) ? 0.99f*(W).z + (P).z*(1.f + (D).z*(W).z) : 0.99f*(W).z; \
         (W).w = (F3) ? 0.99f*(W).w + (P).w*(1.f + (D).w*(W).w) : 0.99f*(W).w; } while (0)
// syn accumulate from one w-row pair
#define SYNACC(S0, S1, VM, W0, W1)                                          \
    do { (S0).x = fmaf((VM), fabsf((W0).x), (S0).x);                        \
         (S0).y = fmaf((VM), fabsf((W0).y), (S0).y);                        \
         (S0).z = fmaf((VM), fabsf((W0).z), (S0).z);                        \
         (S0).w = fmaf((VM), fabsf((W0).w), (S0).w);                        \
         (S1).x = fmaf((VM), fabsf((W1).x), (S1).x);                        \
         (S1).y = fmaf((VM), fabsf((W1).y), (S1).y);                        \
         (S1).z = fmaf((VM), fabsf((W1).z), (S1).z);                        \
         (S1).w = fmaf((VM), fabsf((W1).w), (S1).w); } while (0)

    auto window = [&](h16x8 (&Pc)[S], h16x8 (&Pf)[S], int wnd) {
        const int p  = wnd & 1;
        const int t0 = wnd * S;
        const float4 memB0 = mem0, memB1 = mem1, wpB0 = wp0, wpB1 = wp1;

        // ---- slim speculative pass: syn = 0, wp frozen, no barriers ----
        #pragma unroll
        for (int j = 0; j < S; ++j) {
            const float4 a0 = CVTLO(Pc[j]);
            const float4 a1 = CVTHI(Pc[j]);
            int tp = t0 + j + S; if (tp > TT - 1) tp = TT - 1;
            Pf[j] = *(const h16x8*)(hb + (size_t)tp * NN);   // depth-1 fetch

            // spike test on PRE-update mem (reference semantics)
            const float mx = fmaxf(
                fmaxf(fmaxf(mem0.x, mem0.y), fmaxf(mem0.z, mem0.w)),
                fmaxf(fmaxf(mem1.x, mem1.y), fmaxf(mem1.z, mem1.w)));
            if (__builtin_expect(mx > 1.f, 0)) {
                const bool f0 = mem0.x > 1.f, f1 = mem0.y > 1.f,
                           f2 = mem0.z > 1.f, f3 = mem0.w > 1.f;
                const bool f4 = mem1.x > 1.f, f5 = mem1.y > 1.f,
                           f6 = mem1.z > 1.f, f7 = mem1.w > 1.f;
                atomicOr(&s_amask[p], 1 << j);
                if (f0) APUSH(j, n0,     wp0.x, sg0.x);
                if (f1) APUSH(j, n0 + 1, wp0.y, sg0.y);
                if (f2) APUSH(j, n0 + 2, wp0.z, sg0.z);
                if (f3) APUSH(j, n0 + 3, wp0.w, sg0.w);
                if (f4) APUSH(j, n0 + 4, wp1.x, sg1.x);
                if (f5) APUSH(j, n0 + 5, wp1.y, sg1.y);
                if (f6) APUSH(j, n0 + 6, wp1.z, sg1.z);
                if (f7) APUSH(j, n0 + 7, wp1.w, sg1.w);
                MEMUP(mem0, a0, f0, f1, f2, f3);
                MEMUP(mem1, a1, f4, f5, f6, f7);
            } else {
                MEMUP(mem0, a0, false, false, false, false);
                MEMUP(mem1, a1, false, false, false, false);
            }
        }

        RAWBAR();                    // no vmcnt drain: prefetch stays in flight
        const int mask = s_amask[p];

        if (__builtin_expect(mask == 0, 1)) {   // ---- clean window ----
            wp0.x *= P99_8; wp0.y *= P99_8; wp0.z *= P99_8; wp0.w *= P99_8;
            wp1.x *= P99_8; wp1.y *= P99_8; wp1.z *= P99_8; wp1.w *= P99_8;
            if (tid < NOUT) {
                #pragma unroll
                for (int j = 0; j < S; ++j) {
                    o2 = 0.9f * o2;
                    outb[(size_t)(t0 + j) * NOUT] = o2;
                }
            }
            return;
        }

        // ---- dirty window: rollback + exact replay (slim sync) ----
        const int tstar = __ffs(mask) - 1;

        // prefetch t* w-rows early (list exact & complete; cnt block-uniform)
        int cntS = s_acnt[p][tstar]; if (cntS > ACAP) cntS = ACAP;
        int   pidx[4];
        float pval[4];
        float4 wpre0[4], wpre1[4];
        #pragma unroll
        for (int m_ = 0; m_ < 4; ++m_) {
            if (m_ < cntS) {
                pidx[m_]  = s_aidx[p][tstar][m_];
                pval[m_]  = s_aval[p][tstar][m_];
                wpre0[m_] = *(const float4*)(w + (size_t)pidx[m_] * NN + n0);
                wpre1[m_] = *(const float4*)(w + (size_t)pidx[m_] * NN + n0 + 4);
            }
        }

        mem0 = memB0; mem1 = memB1; wp0 = wpB0; wp1 = wpB1;
        #pragma unroll
        for (int j = 0; j < S; ++j) {
            const float4 a0 = CVTLO(Pc[j]);
            const float4 a1 = CVTHI(Pc[j]);
            if (j < tstar) {          // certified spike-free
                MEMUP(mem0, a0, false, false, false, false);
                MEMUP(mem1, a1, false, false, false, false);
                wp0.x *= 0.99f; wp0.y *= 0.99f; wp0.z *= 0.99f; wp0.w *= 0.99f;
                wp1.x *= 0.99f; wp1.y *= 0.99f; wp1.z *= 0.99f; wp1.w *= 0.99f;
                if (tid < NOUT) { o2 = 0.9f * o2;
                                  outb[(size_t)(t0 + j) * NOUT] = o2; }
            } else if (j == tstar) {  // spec list at t* is exact & complete
                const bool f0 = mem0.x > 1.f, f1 = mem0.y > 1.f,  // pre-update
                           f2 = mem0.z > 1.f, f3 = mem0.w > 1.f;
                const bool f4 = mem1.x > 1.f, f5 = mem1.y > 1.f,
                           f6 = mem1.z > 1.f, f7 = mem1.w > 1.f;
                float4 syn0 = {0.f,0.f,0.f,0.f}, syn1 = {0.f,0.f,0.f,0.f};
                #pragma unroll
                for (int m_ = 0; m_ < 4; ++m_) {
                    if (m_ < cntS)
                        SYNACC(syn0, syn1, pval[m_], wpre0[m_], wpre1[m_]);
                }
                for (int m = 4; m < cntS; ++m) {
                    const int nm = s_aidx[p][tstar][m];
                    const float vm = s_aval[p][tstar][m];
                    const float4 w0 = *(const float4*)(w + (size_t)nm * NN + n0);
                    const float4 w1 = *(const float4*)(w + (size_t)nm * NN + n0 + 4);
                    SYNACC(syn0, syn1, vm, w0, w1);
                }
                if (tid < NOUT) {
                    float c = 0.f;
                    for (int m = 0; m < cntS; ++m)
                        c += w_out[(size_t)s_aidx[p][tstar][m] * NOUT + tid];
                    o2 = 0.9f * o2 + c;
                    outb[(size_t)(t0 + j) * NOUT] = o2;
                }
                mem0.x = fmaf(0.9f, mem0.x, a0.x) + syn0.x - (f0 ? 1.f : 0.f);
                mem0.y = fmaf(0.9f, mem0.y, a0.y) + syn0.y - (f1 ? 1.f : 0.f);
                mem0.z = fmaf(0.9f, mem0.z, a0.z) + syn0.z - (f2 ? 1.f : 0.f);
                mem0.w = fmaf(0.9f, mem0.w, a0.w) + syn0.w - (f3 ? 1.f : 0.f);
                mem1.x = fmaf(0.9f, mem1.x, a1.x) + syn1.x - (f4 ? 1.f : 0.f);
                mem1.y = fmaf(0.9f, mem1.y, a1.y) + syn1.y - (f5 ? 1.f : 0.f);
                mem1.z = fmaf(0.9f, mem1.z, a1.z) + syn1.z - (f6 ? 1.f : 0.f);
                mem1.w = fmaf(0.9f, mem1.w, a1.w) + syn1.w - (f7 ? 1.f : 0.f);
                WPUP(wp0, p40, dp0, f0, f1, f2, f3);
                WPUP(wp1, p41, dp1, f4, f5, f6, f7);
            } else {                  // slow step: 1 barrier; exchange only if
                                      // spikes actually landed this step
                const int par = j & 1;
                const bool f0 = mem0.x > 1.f, f1 = mem0.y > 1.f,  // pre-update
                           f2 = mem0.z > 1.f, f3 = mem0.w > 1.f;
                const bool f4 = mem1.x > 1.f, f5 = mem1.y > 1.f,
                           f6 = mem1.z > 1.f, f7 = mem1.w > 1.f;
                if (f0 | f1 | f2 | f3 | f4 | f5 | f6 | f7) {
                    if (f0) BPUSH(par, n0,     wp0.x, sg0.x);
                    if (f1) BPUSH(par, n0 + 1, wp0.y, sg0.y);
                    if (f2) BPUSH(par, n0 + 2, wp0.z, sg0.z);
                    if (f3) BPUSH(par, n0 + 3, wp0.w, sg0.w);
                    if (f4) BPUSH(par, n0 + 4, wp1.x, sg1.x);
                    if (f5) BPUSH(par, n0 + 5, wp1.y, sg1.y);
                    if (f6) BPUSH(par, n0 + 6, wp1.z, sg1.z);
                    if (f7) BPUSH(par, n0 + 7, wp1.w, sg1.w);
                }
                RAWBAR();             // pushes + cnt visible
                int cnt = s_bcnt[par]; if (cnt > BCAP) cnt = BCAP;
                float4 syn0 = {0.f,0.f,0.f,0.f}, syn1 = {0.f,0.f,0.f,0.f};
                if (__builtin_expect(cnt != 0, 0)) {   // rare secondary spikes
                    for (int m = 0; m < cnt; ++m) {
                        const int nm = s_bidx[par][m];
                        const float vm = s_bval[par][m];
                        const float4 w0 = *(const float4*)(w + (size_t)nm * NN + n0);
                        const float4 w1 = *(const float4*)(w + (size_t)nm * NN + n0 + 4);
                        SYNACC(syn0, syn1, vm, w0, w1);
                    }
                }
                if (tid < NOUT) {
                    float c = 0.f;
                    for (int m = 0; m < cnt; ++m)
                        c += w_out[(size_t)s_bidx[par][m] * NOUT + tid];
                    o2 = 0.9f * o2 + c;
                    outb[(size_t)(t0 + j) * NOUT] = o2;
                }
                mem0.x = fmaf(0.9f, mem0.x, a0.x) + syn0.x - (f0 ? 1.f : 0.f);
                mem0.y = fmaf(0.9f, mem0.y, a0.y) + syn0.y - (f1 ? 1.f : 0.f);
                mem0.z = fmaf(0.9f, mem0.z, a0.z) + syn0.z - (f2 ? 1.f : 0.f);
                mem0.w = fmaf(0.9f, mem0.w, a0.w) + syn0.w - (f3 ? 1.f : 0.f);
                mem1.x = fmaf(0.9f, mem1.x, a1.x) + syn1.x - (f4 ? 1.f : 0.f);
                mem1.y = fmaf(0.9f, mem1.y, a1.y) + syn1.y - (f5 ? 1.f : 0.f);
                mem1.z = fmaf(0.9f, mem1.z, a1.z) + syn1.z - (f6 ? 1.f : 0.f);
                mem1.w = fmaf(0.9f, mem1.w, a1.w) + syn1.w - (f7 ? 1.f : 0.f);
                WPUP(wp0, p40, dp0, f0, f1, f2, f3);
                WPUP(wp1, p41, dp1, f4, f5, f6, f7);
                if (__builtin_expect(cnt != 0, 0)) {
                    RAWBAR();         // all reads of B-list done
                    if (tid == 0) s_bcnt[par] = 0;
                }
                // cnt==0: nothing written, buffer already 0 -> no 2nd barrier
            }
        }
        RAWBAR();                     // all A-list reads done before reset
        if (tid < S) s_acnt[p][tid] = 0;
        else if (tid == S) s_amask[p] = 0;
    };

    for (int wnd = 0; wnd < NWIN - 1; wnd += 2) {
        window(PA, PB, wnd);
        window(PB, PA, wnd + 1);
    }
    window(PA, PB, NWIN - 1);   // NWIN-1 = 24 even -> cur is PA ✓
#undef SYNACC
#undef WPUP
#undef MEMUP
#undef BPUSH
#undef APUSH
#undef CVTHI
#undef CVTLO
#undef RAWBAR
}

// ---------------- launch ----------------------------------------------------
extern "C" void kernel_launch(void* const* d_in, const int* in_sizes, int n_in,
                              void* d_out, int out_size, void* d_ws, size_t ws_size,
                              hipStream_t stream) {
    (void)in_sizes; (void)n_in; (void)out_size; (void)ws_size;
    const float* inputs  = (const float*)d_in[0];
    const float* w       = (const float*)d_in[1];
    const float* w_in    = (const float*)d_in[2];
    const float* w_out   = (const float*)d_in[3];
    const float* w_signs = (const float*)d_in[4];
    const float* p       = (const float*)d_in[5];
    float* out = (float*)d_out;

    const size_t H1B = (size_t)BB * TT * NN * 2;      // 52,428,800 (h1 fp16)
    const size_t APB = (size_t)800 * 4096 * 2;        //  6,553,600 (A packed)

    _Float16* h1 = (_Float16*)d_ws;
    ushort*   Ap = (ushort*)((char*)d_ws + H1B);
    ushort*   Bp = (ushort*)((char*)d_ws + H1B + APB);

    repack_a<<<800, 256, 0, stream>>>(inputs, Ap);
    repack_b<<<128, 256, 0, stream>>>(w_in, Bp);

    dim3 gg(NN / 128, (BB * TT) / 128);               // (16, 100)
    h1_mfma<<<gg, 256, 0, stream>>>(Ap, Bp, h1);

    snn_scan<<<BB, 256, 0, stream>>>(h1, w, w_signs, p, w_out, out);
}

// Round 13
// 87.570 us; speedup vs baseline: 2.1064x; 1.0780x over previous
//
#include <hip/hip_runtime.h>

#define BB   64
#define TT   200
#define NIN  128
#define NN   2048
#define NOUT 20

#define S    8      // speculation window (TT = 25 * S)
#define NWIN 25
#define ACAP 64     // spec spike list capacity per step
#define BCAP 128    // replay spike list capacity

typedef __attribute__((ext_vector_type(8))) short short8;
typedef __attribute__((ext_vector_type(4))) float f32x4;
typedef __attribute__((ext_vector_type(4))) _Float16 h16x4;

// ---- bf16 split: x = hi + lo + eps, |eps| <= 2^-18 |x| ----------------------
__device__ __forceinline__ void bf16split(float x, ushort& h, ushort& l) {
    unsigned u = __float_as_uint(x);
    unsigned hb = (u + 0x7FFFu + ((u >> 16) & 1u)) >> 16;
    h = (ushort)hb;
    float xh = __uint_as_float(hb << 16);
    float xl = x - xh;                      // exact
    unsigned v = __float_as_uint(xl);
    l = (ushort)((v + 0x7FFFu + ((v >> 16) & 1u)) >> 16);
}

// ---- pre-kernel 1: split+repack A (inputs) into MFMA-fragment order --------
// Ap layout: [row_blk=800][kc=4][hl=2][lane=64][8] ushort
__global__ __launch_bounds__(256) void repack_a(
    const float* __restrict__ X, ushort* __restrict__ Ap)
{
    const int blk  = blockIdx.x;            // row_blk 0..799
    const int tid  = threadIdx.x;
    const int kc   = tid >> 6;
    const int lane = tid & 63;
    const int lr   = lane & 15, lg = lane >> 4;

    const float* src = X + (size_t)(blk * 16 + lr) * NIN + kc * 32 + lg * 8;
    float f[8];
    *(float4*)(f)     = *(const float4*)(src);
    *(float4*)(f + 4) = *(const float4*)(src + 4);

    short8 hv, lv;
    #pragma unroll
    for (int j = 0; j < 8; ++j) {
        ushort h, l;
        bf16split(f[j], h, l);
        hv[j] = (short)h; lv[j] = (short)l;
    }
    ushort* dst = Ap + (size_t)(blk * 4 + kc) * 1024 + lane * 8;
    *(short8*)(dst)       = hv;
    *(short8*)(dst + 512) = lv;
}

// ---- pre-kernel 2: split + transpose + repack w_in [128][2048] -------------
// Bp layout: [n_blk=128][kc=4][hl=2][lane=64][8] ushort
__global__ __launch_bounds__(256) void repack_b(
    const float* __restrict__ W, ushort* __restrict__ Bp)
{
    const int blk  = blockIdx.x;            // n_blk 0..127
    const int tid  = threadIdx.x;
    const int kc   = tid >> 6;
    const int lane = tid & 63;
    const int lr   = lane & 15, lg = lane >> 4;

    const float* src = W + (size_t)(kc * 32 + lg * 8) * NN + blk * 16 + lr;
    float f[8];
    #pragma unroll
    for (int j = 0; j < 8; ++j) f[j] = src[(size_t)j * NN];

    short8 hv, lv;
    #pragma unroll
    for (int j = 0; j < 8; ++j) {
        ushort h, l;
        bf16split(f[j], h, l);
        hv[j] = (short)h; lv[j] = (short)l;
    }
    ushort* dst = Bp + (size_t)(blk * 4 + kc) * 1024 + lane * 8;
    *(short8*)(dst)       = hv;
    *(short8*)(dst + 512) = lv;
}

// ---- MFMA GEMM: 256x256 tile, 8 waves, per-kc LDS staging, fp16 epilogue ---
// h1 = Ah*Bh + Ah*Bl + Al*Bh  (verified product set / chain order — bit-exact)
// Halves operand traffic vs 128^2 (205MB -> 102MB) at the measured fixed
// ~10-14 B/cy/CU global_load_lds ingest rate. 128KB LDS (2x 64KB kc-stage),
// 1 block/CU; in-block double-buffer still overlaps stage with MFMA.
__global__ __launch_bounds__(512) void h1_mfma(
    const ushort* __restrict__ Ap, const ushort* __restrict__ Bp,
    _Float16* __restrict__ C)
{
    __shared__ ushort sbuf[2][32][1024];  // [dbuf][A0..15,B16..31][hl*512+...]

    const int l   = blockIdx.y * gridDim.x + blockIdx.x;  // 0..399
    const int nl  = (l & 7) * 50 + (l >> 3);              // bijective (400%8==0)
    const int bx  = nl & 7, by = nl >> 3;

    const int tid  = threadIdx.x;
    const int w_   = tid >> 6, lane = tid & 63;
    const int lr   = lane & 15, lg = lane >> 4;
    const int m0   = by * 256, n0 = bx * 256;
    const int wr   = (w_ >> 2) * 128, wc = (w_ & 3) * 64;   // 2x4 wave grid

    const ushort* pAs = Ap + (size_t)(m0 >> 4) * 4096;    // 16 A chunks
    const ushort* pBs = Bp + (size_t)(n0 >> 4) * 4096;    // 16 B chunks

    // wave w_ stages (chunk,hl) pairs idx = w_*8 .. w_*8+7 of 64 total
#define STAGE(kc, nb)                                                        \
    do {                                                                     \
        _Pragma("unroll")                                                    \
        for (int i_ = 0; i_ < 8; ++i_) {                                     \
            const int idx_   = w_ * 8 + i_;          /* 0..63 */             \
            const int side_  = idx_ >> 5;            /* 0=A, 1=B */          \
            const int chunk_ = (idx_ >> 1) & 15;                             \
            const int hl_    = idx_ & 1;                                     \
            const ushort* g_ = (side_ ? pBs : pAs) + chunk_ * 4096           \
                               + (kc) * 1024 + hl_ * 512 + lane * 8;         \
            ushort* d_ = &sbuf[nb][idx_ >> 1][hl_ * 512];                    \
            __builtin_amdgcn_global_load_lds(                                \
                (const __attribute__((address_space(1))) void*)g_,           \
                (__attribute__((address_space(3))) void*)d_, 16, 0, 0);      \
        }                                                                    \
    } while (0)

    f32x4 acc[8][4];
    const f32x4 z = {0.f, 0.f, 0.f, 0.f};
    #pragma unroll
    for (int rb = 0; rb < 8; ++rb)
        #pragma unroll
        for (int cb = 0; cb < 4; ++cb) acc[rb][cb] = z;

    STAGE(0, 0);
    __syncthreads();    // drains vmcnt: stage(0) complete

    const int ar = (w_ >> 2) * 8;        // A chunk base (0 or 8)
    const int br = 16 + (w_ & 3) * 4;    // B chunk base (16,20,24,28)

    #pragma unroll
    for (int kc = 0; kc < 4; ++kc) {
        const int cb_ = kc & 1;
        if (kc < 3) STAGE(kc + 1, cb_ ^ 1);     // prefetch under compute

        short8 fbh[4], fbl[4];
        #pragma unroll
        for (int cb = 0; cb < 4; ++cb) {
            fbh[cb] = *(const short8*)(&sbuf[cb_][br + cb][lane * 8]);
            fbl[cb] = *(const short8*)(&sbuf[cb_][br + cb][512 + lane * 8]);
        }
        #pragma unroll
        for (int hh = 0; hh < 2; ++hh) {        // rb-halved: caps live VGPRs
            short8 fah[4], fal[4];
            #pragma unroll
            for (int r = 0; r < 4; ++r) {
                fah[r] = *(const short8*)(&sbuf[cb_][ar + hh * 4 + r][lane * 8]);
                fal[r] = *(const short8*)(&sbuf[cb_][ar + hh * 4 + r][512 + lane * 8]);
            }
            #pragma unroll
            for (int r = 0; r < 4; ++r)
                #pragma unroll
                for (int cb = 0; cb < 4; ++cb) {
                    acc[hh * 4 + r][cb] = __builtin_amdgcn_mfma_f32_16x16x32_bf16(
                        fbh[cb], fah[r], acc[hh * 4 + r][cb], 0, 0, 0);
                    acc[hh * 4 + r][cb] = __builtin_amdgcn_mfma_f32_16x16x32_bf16(
                        fbl[cb], fah[r], acc[hh * 4 + r][cb], 0, 0, 0);
                    acc[hh * 4 + r][cb] = __builtin_amdgcn_mfma_f32_16x16x32_bf16(
                        fbh[cb], fal[r], acc[hh * 4 + r][cb], 0, 0, 0);
                }
        }
        if (kc < 3) __syncthreads();   // stage(kc+1) done; buf[cb_] reads done
    }
#undef STAGE

    #pragma unroll
    for (int rb = 0; rb < 8; ++rb) {
        _Float16* Crow = C + (size_t)(m0 + wr + rb * 16 + lr) * NN
                           + n0 + wc + lg * 4;
        #pragma unroll
        for (int cb = 0; cb < 4; ++cb) {
            h16x4 hv;
            hv[0] = (_Float16)acc[rb][cb][0];
            hv[1] = (_Float16)acc[rb][cb][1];
            hv[2] = (_Float16)acc[rb][cb][2];
            hv[3] = (_Float16)acc[rb][cb][3];
            *(h16x4*)(Crow + cb * 16) = hv;
        }
    }
}

// ---------------- Phase 2+3: speculative windowed scan (R10 verbatim) --------
// 512 thr x 4 neurons, S=8. Slim dirty path (1-barrier cnt==0 steps, t* w-row
// prefetch). Verified 43.4us / VGPR 88.
__global__ __launch_bounds__(512) void snn_scan(
    const _Float16* __restrict__ h1, const float* __restrict__ w,
    const float* __restrict__ w_signs, const float* __restrict__ pvec,
    const float* __restrict__ w_out, float* __restrict__ out)
{
    const int b   = blockIdx.x;
    const int tid = threadIdx.x;
    const int n0  = tid << 2;

    __shared__ int   s_amask[2];
    __shared__ int   s_acnt[2][S];
    __shared__ int   s_aidx[2][S][ACAP];
    __shared__ float s_aval[2][S][ACAP];
    __shared__ int   s_bcnt[2];
    __shared__ int   s_bidx[2][BCAP];
    __shared__ float s_bval[2][BCAP];

    if (tid < 2) { s_amask[tid] = 0; s_bcnt[tid] = 0; }
    if (tid < 2 * S) ((int*)s_acnt)[tid] = 0;

    float4 mem = {0.f,0.f,0.f,0.f}, wp = {0.f,0.f,0.f,0.f};
    const float4 p4 = *(const float4*)(pvec + n0);
    const float4 sg = *(const float4*)(w_signs + n0);
    float4 depr;
    depr.x = (p4.x < 0.f) ? 1.f : 0.f;  depr.y = (p4.y < 0.f) ? 1.f : 0.f;
    depr.z = (p4.z < 0.f) ? 1.f : 0.f;  depr.w = (p4.w < 0.f) ? 1.f : 0.f;

    const float P99[S] = {1.0f, 0.99f, 0.9801f, 0.970299f, 0.96059601f,
                          0.9509900499f, 0.941480149401f, 0.93206534790699f};
    const float P99_8 = 0.9227446944279201f;

    const _Float16* hb = h1 + (size_t)b * TT * NN + n0;
    float* outb = out + (size_t)b * TT * NOUT + tid;   // used only if tid<20
    float o2 = 0.f;

    h16x4 PA[S], PB[S];
    #pragma unroll
    for (int j = 0; j < S; ++j) PA[j] = *(const h16x4*)(hb + (size_t)j * NN);
    __syncthreads();   // LDS init visible

#define RAWBAR()                                              \
    do { asm volatile("s_waitcnt lgkmcnt(0)" ::: "memory");   \
         __builtin_amdgcn_s_barrier();                        \
         asm volatile("" ::: "memory"); } while (0)

#define CVT4(v) { (float)(v)[0], (float)(v)[1], (float)(v)[2], (float)(v)[3] }

    auto window = [&](h16x4 (&Pc)[S], h16x4 (&Pf)[S], int wnd) {
        const int p  = wnd & 1;
        const int t0 = wnd * S;
        const float4 memB = mem, wpB = wp;

        // ---- slim speculative pass: syn = 0, wp frozen, no barriers ----
        #pragma unroll
        for (int j = 0; j < S; ++j) {
            const float4 a = CVT4(Pc[j]);
            int tp = t0 + j + S; if (tp > TT - 1) tp = TT - 1;
            Pf[j] = *(const h16x4*)(hb + (size_t)tp * NN);   // depth-1 fetch

            // spike test on PRE-update mem (reference semantics)
            const float mx = fmaxf(fmaxf(mem.x, mem.y), fmaxf(mem.z, mem.w));
            if (__builtin_expect(mx > 1.f, 0)) {
                const bool f0 = mem.x > 1.f, f1 = mem.y > 1.f,
                           f2 = mem.z > 1.f, f3 = mem.w > 1.f;
                atomicOr(&s_amask[p], 1 << j);
                if (f0) { int k = atomicAdd(&s_acnt[p][j], 1);
                          if (k < ACAP) { s_aidx[p][j][k] = n0;
                                          s_aval[p][j][k] = (1.f + wp.x * P99[j]) * sg.x; } }
                if (f1) { int k = atomicAdd(&s_acnt[p][j], 1);
                          if (k < ACAP) { s_aidx[p][j][k] = n0 + 1;
                                          s_aval[p][j][k] = (1.f + wp.y * P99[j]) * sg.y; } }
                if (f2) { int k = atomicAdd(&s_acnt[p][j], 1);
                          if (k < ACAP) { s_aidx[p][j][k] = n0 + 2;
                                          s_aval[p][j][k] = (1.f + wp.z * P99[j]) * sg.z; } }
                if (f3) { int k = atomicAdd(&s_acnt[p][j], 1);
                          if (k < ACAP) { s_aidx[p][j][k] = n0 + 3;
                                          s_aval[p][j][k] = (1.f + wp.w * P99[j]) * sg.w; } }
                mem.x = fmaf(0.9f, mem.x, a.x) - (f0 ? 1.f : 0.f);
                mem.y = fmaf(0.9f, mem.y, a.y) - (f1 ? 1.f : 0.f);
                mem.z = fmaf(0.9f, mem.z, a.z) - (f2 ? 1.f : 0.f);
                mem.w = fmaf(0.9f, mem.w, a.w) - (f3 ? 1.f : 0.f);
            } else {
                mem.x = fmaf(0.9f, mem.x, a.x);
                mem.y = fmaf(0.9f, mem.y, a.y);
                mem.z = fmaf(0.9f, mem.z, a.z);
                mem.w = fmaf(0.9f, mem.w, a.w);
            }
        }

        RAWBAR();                    // no vmcnt drain: prefetch stays in flight
        const int mask = s_amask[p];

        if (__builtin_expect(mask == 0, 1)) {   // ---- clean window ----
            wp.x *= P99_8; wp.y *= P99_8; wp.z *= P99_8; wp.w *= P99_8;
            if (tid < NOUT) {
                #pragma unroll
                for (int j = 0; j < S; ++j) {
                    o2 = 0.9f * o2;
                    outb[(size_t)(t0 + j) * NOUT] = o2;
                }
            }
            return;
        }

        // ---- dirty window: rollback + exact replay (slim sync) ----
        const int tstar = __ffs(mask) - 1;

        // prefetch t* w-rows early: list is exact & complete; hide gather
        // latency under the j<t* register replay. (cnt is block-uniform.)
        int cntS = s_acnt[p][tstar]; if (cntS > ACAP) cntS = ACAP;
        int   pidx[4];
        float pval[4];
        float4 wpre[4];
        #pragma unroll
        for (int m_ = 0; m_ < 4; ++m_) {
            if (m_ < cntS) {
                pidx[m_] = s_aidx[p][tstar][m_];
                pval[m_] = s_aval[p][tstar][m_];
                wpre[m_] = *(const float4*)(w + (size_t)pidx[m_] * NN + n0);
            }
        }

        mem = memB; wp = wpB;
        #pragma unroll
        for (int j = 0; j < S; ++j) {
            const float4 a = CVT4(Pc[j]);
            if (j < tstar) {          // certified spike-free
                mem.x = fmaf(0.9f, mem.x, a.x);
                mem.y = fmaf(0.9f, mem.y, a.y);
                mem.z = fmaf(0.9f, mem.z, a.z);
                mem.w = fmaf(0.9f, mem.w, a.w);
                wp.x *= 0.99f; wp.y *= 0.99f; wp.z *= 0.99f; wp.w *= 0.99f;
                if (tid < NOUT) { o2 = 0.9f * o2;
                                  outb[(size_t)(t0 + j) * NOUT] = o2; }
            } else if (j == tstar) {  // spec list at t* is exact & complete
                const bool f0 = mem.x > 1.f, f1 = mem.y > 1.f,   // pre-update
                           f2 = mem.z > 1.f, f3 = mem.w > 1.f;
                float4 syn = {0.f,0.f,0.f,0.f};
                #pragma unroll
                for (int m_ = 0; m_ < 4; ++m_) {
                    if (m_ < cntS) {
                        syn.x = fmaf(pval[m_], fabsf(wpre[m_].x), syn.x);
                        syn.y = fmaf(pval[m_], fabsf(wpre[m_].y), syn.y);
                        syn.z = fmaf(pval[m_], fabsf(wpre[m_].z), syn.z);
                        syn.w = fmaf(pval[m_], fabsf(wpre[m_].w), syn.w);
                    }
                }
                for (int m = 4; m < cntS; ++m) {
                    const int nm = s_aidx[p][tstar][m];
                    const float vm = s_aval[p][tstar][m];
                    const float4 wr = *(const float4*)(w + (size_t)nm * NN + n0);
                    syn.x = fmaf(vm, fabsf(wr.x), syn.x);
                    syn.y = fmaf(vm, fabsf(wr.y), syn.y);
                    syn.z = fmaf(vm, fabsf(wr.z), syn.z);
                    syn.w = fmaf(vm, fabsf(wr.w), syn.w);
                }
                if (tid < NOUT) {
                    float c = 0.f;
                    for (int m = 0; m < cntS; ++m)
                        c += w_out[(size_t)s_aidx[p][tstar][m] * NOUT + tid];
                    o2 = 0.9f * o2 + c;
                    outb[(size_t)(t0 + j) * NOUT] = o2;
                }
                mem.x = fmaf(0.9f, mem.x, a.x) + syn.x - (f0 ? 1.f : 0.f);
                mem.y = fmaf(0.9f, mem.y, a.y) + syn.y - (f1 ? 1.f : 0.f);
                mem.z = fmaf(0.9f, mem.z, a.z) + syn.z - (f2 ? 1.f : 0.f);
                mem.w = fmaf(0.9f, mem.w, a.w) + syn.w - (f3 ? 1.f : 0.f);
                wp.x = f0 ? 0.99f*wp.x + p4.x*(1.f + depr.x*wp.x) : 0.99f*wp.x;
                wp.y = f1 ? 0.99f*wp.y + p4.y*(1.f + depr.y*wp.y) : 0.99f*wp.y;
                wp.z = f2 ? 0.99f*wp.z + p4.z*(1.f + depr.z*wp.z) : 0.99f*wp.z;
                wp.w = f3 ? 0.99f*wp.w + p4.w*(1.f + depr.w*wp.w) : 0.99f*wp.w;
            } else {                  // slow step: 1 barrier; exchange only if
                                      // spikes actually landed this step
                const int par = j & 1;
                const bool f0 = mem.x > 1.f, f1 = mem.y > 1.f,   // pre-update
                           f2 = mem.z > 1.f, f3 = mem.w > 1.f;
                if (f0 | f1 | f2 | f3) {
                    if (f0) { int k = atomicAdd(&s_bcnt[par], 1); if (k < BCAP) {
                              s_bidx[par][k] = n0;     s_bval[par][k] = (1.f + wp.x) * sg.x; } }
                    if (f1) { int k = atomicAdd(&s_bcnt[par], 1); if (k < BCAP) {
                              s_bidx[par][k] = n0 + 1; s_bval[par][k] = (1.f + wp.y) * sg.y; } }
                    if (f2) { int k = atomicAdd(&s_bcnt[par], 1); if (k < BCAP) {
                              s_bidx[par][k] = n0 + 2; s_bval[par][k] = (1.f + wp.z) * sg.z; } }
                    if (f3) { int k = atomicAdd(&s_bcnt[par], 1); if (k < BCAP) {
                              s_bidx[par][k] = n0 + 3; s_bval[par][k] = (1.f + wp.w) * sg.w; } }
                }
                RAWBAR();             // pushes + cnt visible
                int cnt = s_bcnt[par]; if (cnt > BCAP) cnt = BCAP;
                float4 syn = {0.f,0.f,0.f,0.f};
                if (__builtin_expect(cnt != 0, 0)) {   // rare secondary spikes
                    for (int m = 0; m < cnt; ++m) {
                        const int nm = s_bidx[par][m];
                        const float vm = s_bval[par][m];
                        const float4 wr = *(const float4*)(w + (size_t)nm * NN + n0);
                        syn.x = fmaf(vm, fabsf(wr.x), syn.x);
                        syn.y = fmaf(vm, fabsf(wr.y), syn.y);
                        syn.z = fmaf(vm, fabsf(wr.z), syn.z);
                        syn.w = fmaf(vm, fabsf(wr.w), syn.w);
                    }
                }
                if (tid < NOUT) {
                    float c = 0.f;
                    for (int m = 0; m < cnt; ++m)
                        c += w_out[(size_t)s_bidx[par][m] * NOUT + tid];
                    o2 = 0.9f * o2 + c;
                    outb[(size_t)(t0 + j) * NOUT] = o2;
                }
                mem.x = fmaf(0.9f, mem.x, a.x) + syn.x - (f0 ? 1.f : 0.f);
                mem.y = fmaf(0.9f, mem.y, a.y) + syn.y - (f1 ? 1.f : 0.f);
                mem.z = fmaf(0.9f, mem.z, a.z) + syn.z - (f2 ? 1.f : 0.f);
                mem.w = fmaf(0.9f, mem.w, a.w) + syn.w - (f3 ? 1.f : 0.f);
                wp.x = f0 ? 0.99f*wp.x + p4.x*(1.f + depr.x*wp.x) : 0.99f*wp.x;
                wp.y = f1 ? 0.99f*wp.y + p4.y*(1.f + depr.y*wp.y) : 0.99f*wp.y;
                wp.z = f2 ? 0.99f*wp.z + p4.z*(1.f + depr.z*wp.z) : 0.99f*wp.z;
                wp.w = f3 ? 0.99f*wp.w + p4.w*(1.f + depr.w*wp.w) : 0.99f*wp.w;
                if (__builtin_expect(cnt != 0, 0)) {
                    RAWBAR();         // all reads of B-list done
                    if (tid == 0) s_bcnt[par] = 0;
                }
                // cnt==0: nothing written, buffer already 0 -> no 2nd barrier
            }
        }
        RAWBAR();                     // all A-list reads done before reset
        if (tid < S) s_acnt[p][tid] = 0;
        else if (tid == S) s_amask[p] = 0;
    };

    for (int wnd = 0; wnd < NWIN - 1; wnd += 2) {
        window(PA, PB, wnd);
        window(PB, PA, wnd + 1);
    }
    window(PA, PB, NWIN - 1);   // NWIN-1 = 24 even -> cur is PA ✓
#undef CVT4
#undef RAWBAR
}

// ---------------- launch ----------------------------------------------------
extern "C" void kernel_launch(void* const* d_in, const int* in_sizes, int n_in,
                              void* d_out, int out_size, void* d_ws, size_t ws_size,
                              hipStream_t stream) {
    (void)in_sizes; (void)n_in; (void)out_size; (void)ws_size;
    const float* inputs  = (const float*)d_in[0];
    const float* w       = (const float*)d_in[1];
    const float* w_in    = (const float*)d_in[2];
    const float* w_out   = (const float*)d_in[3];
    const float* w_signs = (const float*)d_in[4];
    const float* p       = (const float*)d_in[5];
    float* out = (float*)d_out;

    const size_t H1B = (size_t)BB * TT * NN * 2;      // 52,428,800 (h1 fp16)
    const size_t APB = (size_t)800 * 4096 * 2;        //  6,553,600 (A packed)

    _Float16* h1 = (_Float16*)d_ws;
    ushort*   Ap = (ushort*)((char*)d_ws + H1B);
    ushort*   Bp = (ushort*)((char*)d_ws + H1B + APB);

    repack_a<<<800, 256, 0, stream>>>(inputs, Ap);
    repack_b<<<128, 256, 0, stream>>>(w_in, Bp);

    dim3 gg(NN / 256, (BB * TT) / 256);               // (8, 50)
    h1_mfma<<<gg, 512, 0, stream>>>(Ap, Bp, h1);

    snn_scan<<<BB, 512, 0, stream>>>(h1, w, w_signs, p, w_out, out);
}